// Round 1
// baseline (723.673 us; speedup 1.0000x reference)
//
#include <hip/hip_runtime.h>
#include <math.h>

#define BSZ 32
#define CCH 192
#define NPIX 784
#define NP 896          // padded N for knn tiling (896 = 7*128)
#define OUTC 384
#define KNN 9
#define CING 96
#define COUTG 96

// ---------------- ws layout ----------------
#define XN_BYTES  (BSZ * CCH * NP * 4)              // 22,020,096
#define SQ_BYTES  (BSZ * NP * 4)                    //    114,688
#define IDX_BYTES (BSZ * NPIX * KNN * 4)            //    903,168
// t buffer: BSZ * 192 * NPIX * 4 = 19,267,584      total ~42.3 MB

__device__ __forceinline__ float gelu_exact(float u) {
    return 0.5f * u * (1.0f + erff(u * 0.70710678118654752440f));
}

// ---------------- K1: normalize features, write padded xn [B][C][NP] + sq [B][NP] ----------------
__global__ __launch_bounds__(256) void k1_normalize(const float* __restrict__ x,
                                                    float* __restrict__ xn,
                                                    float* __restrict__ sq) {
    int b = blockIdx.y;
    int n = blockIdx.x * 256 + threadIdx.x;
    if (n >= NP) return;
    const float* xb = x + (size_t)b * CCH * NPIX;
    float* xnb = xn + (size_t)b * CCH * NP;
    if (n >= NPIX) {
        for (int c = 0; c < CCH; ++c) xnb[c * NP + n] = 0.f;
        sq[b * NP + n] = 1e30f;
        return;
    }
    float ss = 0.f;
    for (int c = 0; c < CCH; ++c) { float v = xb[c * NPIX + n]; ss = fmaf(v, v, ss); }
    float inv = 1.0f / fmaxf(sqrtf(ss), 1e-12f);
    float s2 = 0.f;
    for (int c = 0; c < CCH; ++c) {
        float v = xb[c * NPIX + n] * inv;
        xnb[c * NP + n] = v;
        s2 = fmaf(v, v, s2);
    }
    sq[b * NP + n] = s2;
}

// ---------------- K2: fused gram + top-9 ----------------
#define QT 64
#define NT 128
#define CCHK 16

__device__ __forceinline__ bool lt_pair(float v, int id, float dv, int di) {
    return (v < dv) || (v == dv && id < di);
}

__global__ __launch_bounds__(256) void k2_knn(const float* __restrict__ xn,
                                              const float* __restrict__ sq,
                                              int* __restrict__ nnidx) {
    __shared__ float qfc[CCHK][QT];
    __shared__ float cfc[CCHK][NT];
    __shared__ float tilebuf[QT][NT + 1];
    int b = blockIdx.y;
    int q0 = blockIdx.x * QT;
    int t = threadIdx.x;
    int tq = t >> 5;     // 0..7 : owns queries tq*8 .. tq*8+7
    int tn = t & 31;     // 0..31: owns candidates tn*4 .. tn*4+3
    const float* xnb = xn + (size_t)b * CCH * NP;

    float d9[KNN];
    int   i9[KNN];
#pragma unroll
    for (int r = 0; r < KNN; ++r) { d9[r] = 3.4e38f; i9[r] = 0x7fffffff; }

    for (int n0 = 0; n0 < NP; n0 += NT) {
        float acc[8][4];
#pragma unroll
        for (int i = 0; i < 8; ++i)
#pragma unroll
            for (int j = 0; j < 4; ++j) acc[i][j] = 0.f;

        for (int cc = 0; cc < CCH; cc += CCHK) {
            __syncthreads();
#pragma unroll
            for (int i = t; i < CCHK * QT; i += 256) {
                int ci = i >> 6, qi = i & 63;
                qfc[ci][qi] = xnb[(cc + ci) * NP + q0 + qi];
            }
#pragma unroll
            for (int i = t; i < CCHK * NT; i += 256) {
                int ci = i >> 7, ni = i & 127;
                cfc[ci][ni] = xnb[(cc + ci) * NP + n0 + ni];
            }
            __syncthreads();
#pragma unroll
            for (int ci = 0; ci < CCHK; ++ci) {
                const float4 qa = *(const float4*)&qfc[ci][tq * 8];
                const float4 qb = *(const float4*)&qfc[ci][tq * 8 + 4];
                const float4 cv = *(const float4*)&cfc[ci][tn * 4];
                float qv[8] = {qa.x, qa.y, qa.z, qa.w, qb.x, qb.y, qb.z, qb.w};
                float cw[4] = {cv.x, cv.y, cv.z, cv.w};
#pragma unroll
                for (int i = 0; i < 8; ++i)
#pragma unroll
                    for (int j = 0; j < 4; ++j)
                        acc[i][j] = fmaf(qv[i], cw[j], acc[i][j]);
            }
        }

        // dist ordering value: sq[n] - 2*dot  (sq[q] constant per query -> dropped)
        float sqn[4];
#pragma unroll
        for (int j = 0; j < 4; ++j) sqn[j] = sq[b * NP + n0 + tn * 4 + j];
#pragma unroll
        for (int i = 0; i < 8; ++i)
#pragma unroll
            for (int j = 0; j < 4; ++j)
                tilebuf[tq * 8 + i][tn * 4 + j] = fmaf(-2.f, acc[i][j], sqn[j]);
        __syncthreads();

        if (t < QT) {
            for (int j = 0; j < NT; ++j) {
                float v = tilebuf[t][j];
                int id = n0 + j;
                if (lt_pair(v, id, d9[KNN - 1], i9[KNN - 1])) {
                    // static-index sorted insert (avoid scratch)
                    bool cprev = true;
#pragma unroll
                    for (int p = KNN - 1; p >= 0; --p) {
                        bool cp = (p == 0) ? false : lt_pair(v, id, d9[p - 1], i9[p - 1]);
                        float nd = cp ? d9[p - 1] : (cprev ? v : d9[p]);
                        int nid = cp ? i9[p - 1] : (cprev ? id : i9[p]);
                        d9[p] = nd; i9[p] = nid;
                        cprev = cp;
                    }
                }
            }
        }
        // next iteration's first __syncthreads orders merge-read before tilebuf rewrite
    }

    int q = q0 + t;
    if (t < QT && q < NPIX) {
#pragma unroll
        for (int r = 0; r < KNN; ++r) nnidx[((size_t)b * NPIX + q) * KNN + r] = i9[r];
    }
}

// ---------------- K3: t[og,n] = dot96(w[og], x[half,:,n]); fused gelu for groups 0/1 ----------------
#define NT3 128
__global__ __launch_bounds__(256) void k3_proj(const float* __restrict__ x,
                                               const float* __restrict__ w,
                                               const float* __restrict__ bias,
                                               float* __restrict__ out,
                                               float* __restrict__ tbuf) {
    __shared__ float wgT[CING][COUTG + 1];   // [c][og]
    __shared__ float xc[16][NT3];
    int nt = blockIdx.x;     // 0..6
    int g  = blockIdx.y;     // 0..3
    int b  = blockIdx.z;
    int t  = threadIdx.x;
    int n0 = nt * NT3;
    int tog = t >> 4;        // 0..15 : og = tog*6 .. +5
    int tn  = t & 15;        // n = n0 + tn*8 .. +7

    for (int i = t; i < CING * COUTG; i += 256) {
        int og = i / 96, c = i - og * 96;
        wgT[c][og] = w[(g * COUTG + og) * CING + c];
    }

    float acc[6][8];
#pragma unroll
    for (int i = 0; i < 6; ++i)
#pragma unroll
        for (int j = 0; j < 8; ++j) acc[i][j] = 0.f;

    int chalf = (g & 1) * CING;
    for (int cc = 0; cc < CING; cc += 16) {
        __syncthreads();
#pragma unroll
        for (int i = t; i < 16 * NT3; i += 256) {
            int ci = i >> 7, ni = i & 127;
            int gn = n0 + ni;
            xc[ci][ni] = (gn < NPIX) ? x[((size_t)b * CCH + chalf + cc + ci) * NPIX + gn] : 0.f;
        }
        __syncthreads();
#pragma unroll
        for (int ci = 0; ci < 16; ++ci) {
            float wv[6];
#pragma unroll
            for (int i = 0; i < 6; ++i) wv[i] = wgT[cc + ci][tog * 6 + i];
            const float4 xa = *(const float4*)&xc[ci][tn * 8];
            const float4 xb2 = *(const float4*)&xc[ci][tn * 8 + 4];
            float xv[8] = {xa.x, xa.y, xa.z, xa.w, xb2.x, xb2.y, xb2.z, xb2.w};
#pragma unroll
            for (int i = 0; i < 6; ++i)
#pragma unroll
                for (int j = 0; j < 8; ++j)
                    acc[i][j] = fmaf(wv[i], xv[j], acc[i][j]);
        }
    }

#pragma unroll
    for (int i = 0; i < 6; ++i) {
        int og = tog * 6 + i;
        int ogg = g * COUTG + og;
        float bv = bias[ogg];
#pragma unroll
        for (int j = 0; j < 8; ++j) {
            int n = n0 + tn * 8 + j;
            if (n < NPIX) {
                if (g < 2)
                    out[((size_t)b * OUTC + ogg) * NPIX + n] = gelu_exact(acc[i][j] + bv);
                else
                    tbuf[((size_t)b * 192 + (g - 2) * COUTG + og) * NPIX + n] = acc[i][j];
            }
        }
    }
}

// ---------------- K4: groups 2/3  out = max_k gelu(t[idx_k] - t[n] + bias) ----------------
__global__ __launch_bounds__(256) void k4_gather(const float* __restrict__ tbuf,
                                                 const int* __restrict__ nnidx,
                                                 const float* __restrict__ bias,
                                                 float* __restrict__ out) {
    __shared__ float trow[NPIX];
    int og2 = blockIdx.x;    // 0..191
    int b = blockIdx.y;
    int t = threadIdx.x;
    const float* tr = tbuf + ((size_t)b * 192 + og2) * NPIX;
    for (int i = t; i < NPIX; i += 256) trow[i] = tr[i];
    __syncthreads();
    float bv = bias[192 + og2];
    for (int n = t; n < NPIX; n += 256) {
        float ti = trow[n];
        const int* ip = nnidx + ((size_t)b * NPIX + n) * KNN;
        float m = -3.4e38f;
#pragma unroll
        for (int k = 0; k < KNN; ++k) {
            int j = ip[k];
            float u = trow[j] - ti + bv;
            m = fmaxf(m, gelu_exact(u));
        }
        out[((size_t)b * OUTC + 192 + og2) * NPIX + n] = m;
    }
}

extern "C" void kernel_launch(void* const* d_in, const int* in_sizes, int n_in,
                              void* d_out, int out_size, void* d_ws, size_t ws_size,
                              hipStream_t stream) {
    const float* x    = (const float*)d_in[0];
    const float* w    = (const float*)d_in[1];
    const float* bias = (const float*)d_in[2];
    float* out = (float*)d_out;
    char* ws = (char*)d_ws;

    float* xn    = (float*)(ws);
    float* sq    = (float*)(ws + XN_BYTES);
    int*   nnidx = (int*)  (ws + XN_BYTES + SQ_BYTES);
    float* tbuf  = (float*)(ws + XN_BYTES + SQ_BYTES + IDX_BYTES);

    k1_normalize<<<dim3((NP + 255) / 256, BSZ), 256, 0, stream>>>(x, xn, sq);
    k2_knn<<<dim3((NP + QT - 1) / QT, BSZ), 256, 0, stream>>>(xn, sq, nnidx);
    k3_proj<<<dim3(7, 4, BSZ), 256, 0, stream>>>(x, w, bias, out, tbuf);
    k4_gather<<<dim3(192, BSZ), 256, 0, stream>>>(tbuf, nnidx, bias, out);
}

// Round 2
// 337.000 us; speedup vs baseline: 2.1474x; 2.1474x over previous
//
#include <hip/hip_runtime.h>
#include <math.h>

#define BSZ 32
#define CCH 192
#define NPIX 784
#define NP 896          // padded N (896 = 7*128)
#define OUTC 384
#define KNN 9
#define CING 96
#define COUTG 96

typedef short s8v __attribute__((ext_vector_type(8)));
typedef float f4v __attribute__((ext_vector_type(4)));

// ---------------- ws layout ----------------
#define XHI_BYTES ((size_t)BSZ * NP * CCH * 2)      // 11,010,048
#define XLO_BYTES ((size_t)BSZ * NP * CCH * 2)      // 11,010,048
#define SQ_BYTES  ((size_t)BSZ * NP * 4)            //    114,688
#define IDX_BYTES ((size_t)BSZ * NPIX * KNN * 4)    //    903,168
// tbuf: BSZ*192*NPIX*4 = 19,267,584   total ~42.3 MB

__device__ __forceinline__ float gelu_exact(float u) {
    return 0.5f * u * (1.0f + erff(u * 0.70710678118654752440f));
}
__device__ __forceinline__ ushort bf16_rne(float f) {
    uint u = __float_as_uint(f);
    uint r = (u + 0x7fffu + ((u >> 16) & 1u)) >> 16;
    return (ushort)r;
}
__device__ __forceinline__ float bf16f(ushort h) { return __uint_as_float(((uint)h) << 16); }

// ---------------- K1: normalize -> bf16 hi/lo in node-major [b][n][c] + sq ----------------
__global__ __launch_bounds__(256) void k1_normalize(const float* __restrict__ x,
                                                    ushort* __restrict__ xhi,
                                                    ushort* __restrict__ xlo,
                                                    float* __restrict__ sq) {
    __shared__ ushort hs[64][CCH + 4];
    __shared__ ushort ls[64][CCH + 4];
    int b = blockIdx.y;
    int n0 = blockIdx.x * 64;
    int t = threadIdx.x;
    int ln = t >> 2;          // local node 0..63
    int part = t & 3;         // 48 channels each
    int n = n0 + ln;
    const float* xb = x + (size_t)b * CCH * NPIX;

    float ss = 0.f;
    if (n < NPIX) {
        for (int c = part * 48; c < part * 48 + 48; ++c) {
            float v = xb[c * NPIX + n];
            ss = fmaf(v, v, ss);
        }
    }
    ss += __shfl_xor(ss, 1);
    ss += __shfl_xor(ss, 2);
    float inv = 1.0f / fmaxf(sqrtf(ss), 1e-12f);

    float s2 = 0.f;
    for (int c = part * 48; c < part * 48 + 48; ++c) {
        float v = (n < NPIX) ? xb[c * NPIX + n] * inv : 0.f;
        ushort h = bf16_rne(v);
        ushort l = bf16_rne(v - bf16f(h));
        hs[ln][c] = h;
        ls[ln][c] = l;
        s2 = fmaf(v, v, s2);
    }
    s2 += __shfl_xor(s2, 1);
    s2 += __shfl_xor(s2, 2);
    if (part == 0) sq[b * NP + n] = (n < NPIX) ? s2 : 1e30f;

    __syncthreads();
    uint* hdst = (uint*)(xhi + ((size_t)b * NP + n0) * CCH);
    uint* ldst = (uint*)(xlo + ((size_t)b * NP + n0) * CCH);
    for (int i = t; i < 64 * (CCH / 2); i += 256) {
        int row = i / (CCH / 2), col = i - row * (CCH / 2);
        hdst[i] = *(const uint*)((const char*)&hs[row][0] + col * 4);
        ldst[i] = *(const uint*)((const char*)&ls[row][0] + col * 4);
    }
}

// ---------------- K2: MFMA gram (bf16 split) + parallel top-9 ----------------
#define QT2 64
#define NT2 128

__device__ __forceinline__ bool lt_pair(float v, int id, float dv, int di) {
    return (v < dv) || (v == dv && id < di);
}

__global__ __launch_bounds__(256) void k2_knn(const ushort* __restrict__ xhi,
                                              const ushort* __restrict__ xlo,
                                              const float* __restrict__ sq,
                                              int* __restrict__ nnidx) {
    __shared__ float tb[QT2][NT2 + 4];     // 64 x 132 floats = 33.8 KB
    int b = blockIdx.y;
    int q0 = blockIdx.x * QT2;
    int t = threadIdx.x;
    int w = t >> 6;        // wave 0..3
    int l = t & 63;
    int lr = l & 15;       // fragment row/col
    int lk = l >> 4;       // k-group 0..3
    const ushort* hb = xhi + (size_t)b * NP * CCH;
    const ushort* lb = xlo + (size_t)b * NP * CCH;

    // resident A fragments (query rows q0 + w*16 + lr), k = kc*32 + lk*8 + j
    s8v ah[6], al[6];
    {
        const ushort* qh = hb + (size_t)(q0 + w * 16 + lr) * CCH + lk * 8;
        const ushort* ql = lb + (size_t)(q0 + w * 16 + lr) * CCH + lk * 8;
#pragma unroll
        for (int kc = 0; kc < 6; ++kc) {
            ah[kc] = *(const s8v*)(qh + kc * 32);
            al[kc] = *(const s8v*)(ql + kc * 32);
        }
    }

    float d9[KNN];
    int   i9[KNN];
#pragma unroll
    for (int r = 0; r < KNN; ++r) { d9[r] = 3.4e38f; i9[r] = 0x7fffffff; }

    for (int n0 = 0; n0 < NP; n0 += NT2) {
#pragma unroll
        for (int cb = 0; cb < 8; cb += 2) {
            const ushort* ch0 = hb + (size_t)(n0 + cb * 16 + lr) * CCH + lk * 8;
            const ushort* cl0 = lb + (size_t)(n0 + cb * 16 + lr) * CCH + lk * 8;
            const ushort* ch1 = ch0 + (size_t)16 * CCH;
            const ushort* cl1 = cl0 + (size_t)16 * CCH;
            f4v a0h = {0.f, 0.f, 0.f, 0.f}, a0x = {0.f, 0.f, 0.f, 0.f};
            f4v a1h = {0.f, 0.f, 0.f, 0.f}, a1x = {0.f, 0.f, 0.f, 0.f};
#pragma unroll
            for (int kc = 0; kc < 6; ++kc) {
                s8v b0h = *(const s8v*)(ch0 + kc * 32);
                s8v b0l = *(const s8v*)(cl0 + kc * 32);
                s8v b1h = *(const s8v*)(ch1 + kc * 32);
                s8v b1l = *(const s8v*)(cl1 + kc * 32);
                a0h = __builtin_amdgcn_mfma_f32_16x16x32_bf16(ah[kc], b0h, a0h, 0, 0, 0);
                a0x = __builtin_amdgcn_mfma_f32_16x16x32_bf16(ah[kc], b0l, a0x, 0, 0, 0);
                a0x = __builtin_amdgcn_mfma_f32_16x16x32_bf16(al[kc], b0h, a0x, 0, 0, 0);
                a1h = __builtin_amdgcn_mfma_f32_16x16x32_bf16(ah[kc], b1h, a1h, 0, 0, 0);
                a1x = __builtin_amdgcn_mfma_f32_16x16x32_bf16(ah[kc], b1l, a1x, 0, 0, 0);
                a1x = __builtin_amdgcn_mfma_f32_16x16x32_bf16(al[kc], b1h, a1x, 0, 0, 0);
            }
            float sq0 = sq[b * NP + n0 + cb * 16 + lr];
            float sq1 = sq[b * NP + n0 + cb * 16 + 16 + lr];
            // D: col = lane&15 (candidate), row = (lane>>4)*4 + r (query)
#pragma unroll
            for (int r = 0; r < 4; ++r) {
                tb[w * 16 + lk * 4 + r][cb * 16 + lr]      = fmaf(-2.f, a0h[r] + a0x[r], sq0);
                tb[w * 16 + lk * 4 + r][cb * 16 + 16 + lr] = fmaf(-2.f, a1h[r] + a1x[r], sq1);
            }
        }
        __syncthreads();
        {
            int mq = t >> 2, part = t & 3;
#pragma unroll
            for (int i = 0; i < 32; ++i) {
                int col = part + i * 4;
                float v = tb[mq][col];
                int id = n0 + col;
                if (lt_pair(v, id, d9[KNN - 1], i9[KNN - 1])) {
                    bool cprev = true;
#pragma unroll
                    for (int p = KNN - 1; p >= 0; --p) {
                        bool cp = (p == 0) ? false : lt_pair(v, id, d9[p - 1], i9[p - 1]);
                        float nd = cp ? d9[p - 1] : (cprev ? v : d9[p]);
                        int nid = cp ? i9[p - 1] : (cprev ? id : i9[p]);
                        d9[p] = nd; i9[p] = nid;
                        cprev = cp;
                    }
                }
            }
        }
        __syncthreads();
    }

    // dump per-part sorted lists into LDS (overlay on tb) and 4-way merge
    float* dl = &tb[0][0];                 // [64][4][9] floats = 2304
    int*   il = (int*)(dl + QT2 * 4 * KNN);
    {
        int mq = t >> 2, part = t & 3;
#pragma unroll
        for (int r = 0; r < KNN; ++r) {
            dl[(mq * 4 + part) * KNN + r] = d9[r];
            il[(mq * 4 + part) * KNN + r] = i9[r];
        }
    }
    __syncthreads();
    if (t < QT2 && q0 + t < NPIX) {
        int base = t * 4 * KNN;
        size_t ob = ((size_t)b * NPIX + q0 + t) * KNN;
        int pt0 = 0, pt1 = 0, pt2 = 0, pt3 = 0;
#pragma unroll
        for (int r = 0; r < KNN; ++r) {
            float d0v = dl[base + 0 * KNN + pt0]; int i0v = il[base + 0 * KNN + pt0];
            float d1v = dl[base + 1 * KNN + pt1]; int i1v = il[base + 1 * KNN + pt1];
            float d2v = dl[base + 2 * KNN + pt2]; int i2v = il[base + 2 * KNN + pt2];
            float d3v = dl[base + 3 * KNN + pt3]; int i3v = il[base + 3 * KNN + pt3];
            bool w01 = lt_pair(d1v, i1v, d0v, i0v);
            float dA = w01 ? d1v : d0v; int iA = w01 ? i1v : i0v;
            bool w23 = lt_pair(d3v, i3v, d2v, i2v);
            float dB = w23 ? d3v : d2v; int iB = w23 ? i3v : i2v;
            bool wAB = lt_pair(dB, iB, dA, iA);
            int win = wAB ? (w23 ? 3 : 2) : (w01 ? 1 : 0);
            int bi = wAB ? iB : iA;
            nnidx[ob + r] = bi;
            pt0 += (win == 0); pt1 += (win == 1); pt2 += (win == 2); pt3 += (win == 3);
        }
    }
}

// ---------------- K3: t[og,n] = dot96(w[og], x[half,:,n]); fused gelu for groups 0/1 ----------------
#define NT3 128
__global__ __launch_bounds__(256) void k3_proj(const float* __restrict__ x,
                                               const float* __restrict__ w,
                                               const float* __restrict__ bias,
                                               float* __restrict__ out,
                                               float* __restrict__ tbuf) {
    __shared__ float wgT[CING][COUTG + 1];   // [c][og]
    __shared__ float xc[16][NT3];
    int nt = blockIdx.x;     // 0..6
    int g  = blockIdx.y;     // 0..3
    int b  = blockIdx.z;
    int t  = threadIdx.x;
    int n0 = nt * NT3;
    int tog = t >> 4;        // 0..15 : og = tog*6 .. +5
    int tn  = t & 15;        // n = n0 + tn*8 .. +7

    for (int i = t; i < CING * COUTG; i += 256) {
        int og = i / 96, c = i - og * 96;
        wgT[c][og] = w[(g * COUTG + og) * CING + c];
    }

    float acc[6][8];
#pragma unroll
    for (int i = 0; i < 6; ++i)
#pragma unroll
        for (int j = 0; j < 8; ++j) acc[i][j] = 0.f;

    int chalf = (g & 1) * CING;
    for (int cc = 0; cc < CING; cc += 16) {
        __syncthreads();
#pragma unroll
        for (int i = t; i < 16 * NT3; i += 256) {
            int ci = i >> 7, ni = i & 127;
            int gn = n0 + ni;
            xc[ci][ni] = (gn < NPIX) ? x[((size_t)b * CCH + chalf + cc + ci) * NPIX + gn] : 0.f;
        }
        __syncthreads();
#pragma unroll
        for (int ci = 0; ci < 16; ++ci) {
            float wv[6];
#pragma unroll
            for (int i = 0; i < 6; ++i) wv[i] = wgT[cc + ci][tog * 6 + i];
            const float4 xa = *(const float4*)&xc[ci][tn * 8];
            const float4 xb2 = *(const float4*)&xc[ci][tn * 8 + 4];
            float xv[8] = {xa.x, xa.y, xa.z, xa.w, xb2.x, xb2.y, xb2.z, xb2.w};
#pragma unroll
            for (int i = 0; i < 6; ++i)
#pragma unroll
                for (int j = 0; j < 8; ++j)
                    acc[i][j] = fmaf(wv[i], xv[j], acc[i][j]);
        }
    }

#pragma unroll
    for (int i = 0; i < 6; ++i) {
        int og = tog * 6 + i;
        int ogg = g * COUTG + og;
        float bv = bias[ogg];
#pragma unroll
        for (int j = 0; j < 8; ++j) {
            int n = n0 + tn * 8 + j;
            if (n < NPIX) {
                if (g < 2)
                    out[((size_t)b * OUTC + ogg) * NPIX + n] = gelu_exact(acc[i][j] + bv);
                else
                    tbuf[((size_t)b * 192 + (g - 2) * COUTG + og) * NPIX + n] = acc[i][j];
            }
        }
    }
}

// ---------------- K4: groups 2/3  out = max_k gelu(t[idx_k] - t[n] + bias) ----------------
// gelu is unimodal (min at u*≈-0.752): max over set = max(gelu(umin), gelu(umax))
__global__ __launch_bounds__(256) void k4_gather(const float* __restrict__ tbuf,
                                                 const int* __restrict__ nnidx,
                                                 const float* __restrict__ bias,
                                                 float* __restrict__ out) {
    __shared__ float trow[NPIX];
    int og2 = blockIdx.x;    // 0..191
    int b = blockIdx.y;
    int t = threadIdx.x;
    const float* tr = tbuf + ((size_t)b * 192 + og2) * NPIX;
    for (int i = t; i < NPIX; i += 256) trow[i] = tr[i];
    __syncthreads();
    float bv = bias[192 + og2];
    for (int n = t; n < NPIX; n += 256) {
        float ti = trow[n];
        const int* ip = nnidx + ((size_t)b * NPIX + n) * KNN;
        float umin = 3.4e38f, umax = -3.4e38f;
#pragma unroll
        for (int k = 0; k < KNN; ++k) {
            int j = ip[k];
            float u = trow[j] - ti + bv;
            umin = fminf(umin, u);
            umax = fmaxf(umax, u);
        }
        float m = fmaxf(gelu_exact(umin), gelu_exact(umax));
        out[((size_t)b * OUTC + 192 + og2) * NPIX + n] = m;
    }
}

extern "C" void kernel_launch(void* const* d_in, const int* in_sizes, int n_in,
                              void* d_out, int out_size, void* d_ws, size_t ws_size,
                              hipStream_t stream) {
    const float* x    = (const float*)d_in[0];
    const float* w    = (const float*)d_in[1];
    const float* bias = (const float*)d_in[2];
    float* out = (float*)d_out;
    char* ws = (char*)d_ws;

    ushort* xhi  = (ushort*)(ws);
    ushort* xlo  = (ushort*)(ws + XHI_BYTES);
    float*  sq   = (float*) (ws + XHI_BYTES + XLO_BYTES);
    int*    nnidx= (int*)   (ws + XHI_BYTES + XLO_BYTES + SQ_BYTES);
    float*  tbuf = (float*) (ws + XHI_BYTES + XLO_BYTES + SQ_BYTES + IDX_BYTES);

    k1_normalize<<<dim3(NP / 64, BSZ), 256, 0, stream>>>(x, xhi, xlo, sq);
    k2_knn<<<dim3((NPIX + QT2 - 1) / QT2, BSZ), 256, 0, stream>>>(xhi, xlo, sq, nnidx);
    k3_proj<<<dim3(7, 4, BSZ), 256, 0, stream>>>(x, w, bias, out, tbuf);
    k4_gather<<<dim3(192, BSZ), 256, 0, stream>>>(tbuf, nnidx, bias, out);
}